// Round 9
// baseline (349.647 us; speedup 1.0000x reference)
//
#include <hip/hip_runtime.h>

#define NBATCH 256
#define P 1024
#define Q 128
#define NS_LOOP 10

typedef _Float16 half8 __attribute__((ext_vector_type(8)));
typedef float f32x4 __attribute__((ext_vector_type(4)));
struct Half4 { _Float16 x, y, z, w; };   // 8 bytes

// Swizzled fp16 storage for 128x128 matrices:
// element (r,c) -> Half4 slot r*32 + ((c>>2) ^ (r&15)), component c&3.
__device__ __forceinline__ half8 frag_ld(const Half4* S, int rowbase, int slotbase, int lane) {
    const int r = rowbase + (lane & 15);
    const int g = (lane >> 4);
    const int rx = r & 15;
    const Half4 h1 = S[r * 32 + ((slotbase + g) ^ rx)];
    const Half4 h2 = S[r * 32 + ((slotbase + g + 4) ^ rx)];
    half8 v;
    v[0] = h1.x; v[1] = h1.y; v[2] = h1.z; v[3] = h1.w;
    v[4] = h2.x; v[5] = h2.y; v[6] = h2.z; v[7] = h2.w;
    return v;
}

// C-fragment position, stored TRANSPOSED (ok: all iterates symmetric to O(eps)).
__device__ __forceinline__ int cpos(int RB, int CB, int lane) {
    const int r = CB + (lane & 15);
    const int s = (RB >> 2) + (lane >> 4);
    return r * 32 + (s ^ (r & 15));
}

__device__ __forceinline__ f32x4 cread(const Half4* S, int p) {
    const Half4 h = S[p];
    f32x4 v;
    v[0] = (float)h.x; v[1] = (float)h.y; v[2] = (float)h.z; v[3] = (float)h.w;
    return v;
}

__device__ __forceinline__ void cwrite(Half4* S, int p, f32x4 v) {
    Half4 h;
    h.x = (_Float16)v[0]; h.y = (_Float16)v[1]; h.z = (_Float16)v[2]; h.w = (_Float16)v[3];
    S[p] = h;
}

// ---------------------------------------------------------------------------
// Kernel 1: partial gram. Block (n, part) computes temp[part-rows]^T temp
// over P/npart rows -> gpart[(n*npart+part)]. npart blocks/batch raises
// occupancy (r8: 1 block/CU, VALUBusy 36% -> latency-bound at 178us).
// ---------------------------------------------------------------------------
__global__ __launch_bounds__(256) void gram_kernel(
    const float* __restrict__ X, const float* __restrict__ G,
    const float* __restrict__ lrp, float* __restrict__ gpart, int npart)
{
    const int n = blockIdx.x / npart;
    const int part = blockIdx.x - n * npart;
    const int rows = P / npart;
    const float lr = *lrp;
    const float* xb = X + (size_t)n * P * Q;
    const float* gb = G + (size_t)n * P * Q;
    __shared__ float sT[32][Q];  // 16 KB
    const int tid = threadIdx.x;
    const int ty = tid >> 4, tx = tid & 15;

    float acc[8][8];
#pragma unroll
    for (int i = 0; i < 8; ++i)
#pragma unroll
        for (int j = 0; j < 8; ++j) acc[i][j] = 0.0f;

    for (int p0 = part * rows; p0 < (part + 1) * rows; p0 += 32) {
#pragma unroll
        for (int t = 0; t < 4; ++t) {
            const int idx = tid + t * 256;
            float4 xv = reinterpret_cast<const float4*>(xb + (size_t)p0 * Q)[idx];
            float4 gv = reinterpret_cast<const float4*>(gb + (size_t)p0 * Q)[idx];
            float4 tv;
            tv.x = xv.x - lr * gv.x; tv.y = xv.y - lr * gv.y;
            tv.z = xv.z - lr * gv.z; tv.w = xv.w - lr * gv.w;
            reinterpret_cast<float4*>(&sT[0][0])[idx] = tv;
        }
        __syncthreads();
        for (int p = 0; p < 32; ++p) {
            float4 a0 = *reinterpret_cast<const float4*>(&sT[p][ty * 8]);
            float4 a1 = *reinterpret_cast<const float4*>(&sT[p][ty * 8 + 4]);
            float4 b0 = *reinterpret_cast<const float4*>(&sT[p][tx * 8]);
            float4 b1 = *reinterpret_cast<const float4*>(&sT[p][tx * 8 + 4]);
            float a[8] = {a0.x, a0.y, a0.z, a0.w, a1.x, a1.y, a1.z, a1.w};
            float b[8] = {b0.x, b0.y, b0.z, b0.w, b1.x, b1.y, b1.z, b1.w};
#pragma unroll
            for (int i = 0; i < 8; ++i)
#pragma unroll
                for (int j = 0; j < 8; ++j) acc[i][j] += a[i] * b[j];
        }
        __syncthreads();
    }
    float* gm = gpart + ((size_t)n * npart + part) * Q * Q;
#pragma unroll
    for (int i = 0; i < 8; ++i) {
#pragma unroll
        for (int j = 0; j < 2; ++j) {
            float4 v = make_float4(acc[i][4 * j + 0], acc[i][4 * j + 1],
                                   acc[i][4 * j + 2], acc[i][4 * j + 3]);
            reinterpret_cast<float4*>(&gm[(size_t)(ty * 8 + i) * Q + tx * 8])[j] = v;
        }
    }
}

// ---------------------------------------------------------------------------
// Kernel 2: Newton-Schulz (fp16 MFMA). Sums the npart partial grams at load,
// writes the summed fp32 gram out for the refiner, then iterates as before.
// ---------------------------------------------------------------------------
__global__ __launch_bounds__(512) void ns_kernel(
    const float* __restrict__ gpart, int npart,
    float* __restrict__ gram, float* __restrict__ Zg)
{
    __shared__ __align__(16) unsigned char pool[98304];
    Half4* bufA = (Half4*)pool;
    Half4* bufB = (Half4*)(pool + 32768);
    Half4* sZh  = (Half4*)(pool + 65536);
    __shared__ float sRed[8];

    const int n = blockIdx.x;
    const int tid = threadIdx.x;
    const float* gp = gpart + (size_t)n * npart * Q * Q;
    float* gmo = gram + (size_t)n * Q * Q;

    float4 gv[8];
    float ss = 0.0f;
#pragma unroll
    for (int t = 0; t < 8; ++t) {
        const int idx = tid + t * 512;
        float4 v = ((const float4*)gp)[idx];
        for (int pp = 1; pp < npart; ++pp) {
            const float4 w = ((const float4*)(gp + (size_t)pp * Q * Q))[idx];
            v.x += w.x; v.y += w.y; v.z += w.z; v.w += w.w;
        }
        gv[t] = v;
        ((float4*)gmo)[idx] = v;   // summed gram for refine_kernel
        ss += v.x * v.x + v.y * v.y + v.z * v.z + v.w * v.w;
    }
#pragma unroll
    for (int off = 32; off > 0; off >>= 1) ss += __shfl_down(ss, off, 64);
    if ((tid & 63) == 0) sRed[tid >> 6] = ss;
    __syncthreads();
    float csum = 0.0f;
#pragma unroll
    for (int w = 0; w < 8; ++w) csum += sRed[w];
    const float c = sqrtf(csum);
    const float rc = 1.0f / c;
    const float rs = 1.0f / sqrtf(c);

#pragma unroll
    for (int t = 0; t < 8; ++t) {
        const int idx = tid + t * 512;
        const int row = idx >> 5, c4 = idx & 31;
        const int slot = row * 32 + (c4 ^ (row & 15));
        float wv[4], zv[4];
        wv[0] = gv[t].x * rc; wv[1] = gv[t].y * rc;
        wv[2] = gv[t].z * rc; wv[3] = gv[t].w * rc;
#pragma unroll
        for (int j = 0; j < 4; ++j)
            zv[j] = -0.5f * wv[j] + (((row >> 2) == c4 && (row & 3) == j) ? 1.5f : 0.0f);
        Half4 wh, zh;
        wh.x = (_Float16)wv[0]; wh.y = (_Float16)wv[1]; wh.z = (_Float16)wv[2]; wh.w = (_Float16)wv[3];
        zh.x = (_Float16)zv[0]; zh.y = (_Float16)zv[1]; zh.z = (_Float16)zv[2]; zh.w = (_Float16)zv[3];
        bufA[slot] = wh;
        sZh[slot] = zh;
    }
    __syncthreads();

    const int lane = tid & 63;
    const int wid = tid >> 6;
    const int RB = wid * 16;
    const f32x4 zero4 = {0.0f, 0.0f, 0.0f, 0.0f};
    Half4* cur = bufA;
    Half4* scr = bufB;

    for (int it = 0; it < NS_LOOP; ++it) {
        f32x4 a1[8];
#pragma unroll
        for (int fj = 0; fj < 8; ++fj) a1[fj] = zero4;
#pragma unroll
        for (int kb = 0; kb < 4; ++kb) {
            const half8 af = frag_ld(cur, RB, kb * 8, lane);
#pragma unroll
            for (int fj = 0; fj < 8; ++fj) {
                const half8 bf = frag_ld(cur, fj * 16, kb * 8, lane);
                a1[fj] = __builtin_amdgcn_mfma_f32_16x16x32_f16(af, bf, a1[fj], 0, 0, 0);
            }
        }
#pragma unroll
        for (int fj = 0; fj < 8; ++fj) {
            const int p = cpos(RB, fj * 16, lane);
            cwrite(scr, p, 1.5f * cread(cur, p) - 0.5f * a1[fj]);
        }
        __syncthreads();

        f32x4 a2[8];
#pragma unroll
        for (int fj = 0; fj < 8; ++fj) a2[fj] = zero4;
#pragma unroll
        for (int kb = 0; kb < 4; ++kb) {
            const half8 af = frag_ld(scr, RB, kb * 8, lane);
#pragma unroll
            for (int fj = 0; fj < 8; ++fj) {
                const half8 bf = frag_ld(cur, fj * 16, kb * 8, lane);
                a2[fj] = __builtin_amdgcn_mfma_f32_16x16x32_f16(af, bf, a2[fj], 0, 0, 0);
            }
        }
        f32x4 wn[8];
#pragma unroll
        for (int fj = 0; fj < 8; ++fj) {
            const int p = cpos(RB, fj * 16, lane);
            wn[fj] = 1.5f * cread(scr, p) - 0.5f * a2[fj];
        }
        __syncthreads();
#pragma unroll
        for (int fj = 0; fj < 8; ++fj)
            cwrite(scr, cpos(RB, fj * 16, lane), wn[fj]);
        __syncthreads();

        f32x4 a3[8];
#pragma unroll
        for (int fj = 0; fj < 8; ++fj) a3[fj] = zero4;
#pragma unroll
        for (int kb = 0; kb < 4; ++kb) {
            const half8 af = frag_ld(scr, RB, kb * 8, lane);
#pragma unroll
            for (int fj = 0; fj < 8; ++fj) {
                const half8 bf = frag_ld(sZh, fj * 16, kb * 8, lane);
                a3[fj] = __builtin_amdgcn_mfma_f32_16x16x32_f16(af, bf, a3[fj], 0, 0, 0);
            }
        }
        f32x4 zn[8];
#pragma unroll
        for (int fj = 0; fj < 8; ++fj) {
            const int p = cpos(RB, fj * 16, lane);
            zn[fj] = 1.5f * cread(sZh, p) - 0.5f * a3[fj];
        }
        __syncthreads();
#pragma unroll
        for (int fj = 0; fj < 8; ++fj)
            cwrite(sZh, cpos(RB, fj * 16, lane), zn[fj]);
        __syncthreads();

        Half4* tmp = cur; cur = scr; scr = tmp;
    }

    float* zo = Zg + (size_t)n * Q * Q;
#pragma unroll
    for (int t = 0; t < 8; ++t) {
        const int idx = tid + t * 512;
        const int row = idx >> 5, c4 = idx & 31;
        const Half4 h = sZh[row * 32 + (c4 ^ (row & 15))];
        float4 o;
        o.x = (float)h.x * rs; o.y = (float)h.y * rs;
        o.z = (float)h.z * rs; o.w = (float)h.w * rs;
        ((float4*)(zo + row * Q))[c4] = o;
    }
}

// ---------------------------------------------------------------------------
// Kernel 3: one fp32 NS refinement step (counter-clean).
// ---------------------------------------------------------------------------
__global__ __launch_bounds__(512) void refine_kernel(
    const float* __restrict__ gram, float* __restrict__ Zg)
{
    __shared__ float sY[Q * Q];
    __shared__ float sU[Q * Q];
    __shared__ float sR[32 * Q];
    const int n = blockIdx.x;
    const int tid = threadIdx.x;
    const float* gm = gram + (size_t)n * Q * Q;
    float* zg = Zg + (size_t)n * Q * Q;
    const int ty = tid >> 5, tx = tid & 31;

#pragma unroll
    for (int t = 0; t < 8; ++t) {
        const int idx = tid + t * 512;
        ((float4*)sY)[idx] = ((const float4*)zg)[idx];
    }
    __syncthreads();

    {
        float acc[8][4];
#pragma unroll
        for (int i = 0; i < 8; ++i)
#pragma unroll
            for (int j = 0; j < 4; ++j) acc[i][j] = 0.0f;
        for (int k = 0; k < Q; ++k) {
            float a[8];
#pragma unroll
            for (int i = 0; i < 8; ++i) a[i] = sY[(ty * 8 + i) * Q + k];
            const float4 bv = ((const float4*)(sY + k * Q))[tx];
            const float b[4] = {bv.x, bv.y, bv.z, bv.w};
#pragma unroll
            for (int i = 0; i < 8; ++i)
#pragma unroll
                for (int j = 0; j < 4; ++j) acc[i][j] += a[i] * b[j];
        }
#pragma unroll
        for (int i = 0; i < 8; ++i) {
            float4 v = make_float4(acc[i][0], acc[i][1], acc[i][2], acc[i][3]);
            ((float4*)(sU + (ty * 8 + i) * Q))[tx] = v;
        }
    }
    __syncthreads();

    for (int ch = 0; ch < 4; ++ch) {
        const int r0 = ch * 32 + ty * 2;
        float acc[2][4];
#pragma unroll
        for (int i = 0; i < 2; ++i)
#pragma unroll
            for (int j = 0; j < 4; ++j) acc[i][j] = 0.0f;
        for (int k = 0; k < Q; ++k) {
            const float a0 = sY[(r0 + 0) * Q + k];
            const float a1 = sY[(r0 + 1) * Q + k];
            const float4 bv = ((const float4*)(gm + (size_t)k * Q))[tx];
            acc[0][0] += a0 * bv.x; acc[0][1] += a0 * bv.y;
            acc[0][2] += a0 * bv.z; acc[0][3] += a0 * bv.w;
            acc[1][0] += a1 * bv.x; acc[1][1] += a1 * bv.y;
            acc[1][2] += a1 * bv.z; acc[1][3] += a1 * bv.w;
        }
        __syncthreads();
#pragma unroll
        for (int i = 0; i < 2; ++i) {
            float4 v = make_float4(acc[i][0], acc[i][1], acc[i][2], acc[i][3]);
            ((float4*)(sR + (ty * 2 + i) * Q))[tx] = v;
        }
        __syncthreads();

        float acc2[2][4];
#pragma unroll
        for (int i = 0; i < 2; ++i)
#pragma unroll
            for (int j = 0; j < 4; ++j) acc2[i][j] = 0.0f;
        for (int k = 0; k < Q; ++k) {
            const float a0 = sR[(ty * 2 + 0) * Q + k];
            const float a1 = sR[(ty * 2 + 1) * Q + k];
            const float4 bv = ((const float4*)(sU + k * Q))[tx];
            acc2[0][0] += a0 * bv.x; acc2[0][1] += a0 * bv.y;
            acc2[0][2] += a0 * bv.z; acc2[0][3] += a0 * bv.w;
            acc2[1][0] += a1 * bv.x; acc2[1][1] += a1 * bv.y;
            acc2[1][2] += a1 * bv.z; acc2[1][3] += a1 * bv.w;
        }
#pragma unroll
        for (int i = 0; i < 2; ++i) {
            const float4 yv = ((const float4*)(sY + (r0 + i) * Q))[tx];
            float4 o;
            o.x = 1.5f * yv.x - 0.5f * acc2[i][0];
            o.y = 1.5f * yv.y - 0.5f * acc2[i][1];
            o.z = 1.5f * yv.z - 0.5f * acc2[i][2];
            o.w = 1.5f * yv.w - 0.5f * acc2[i][3];
            ((float4*)(zg + (size_t)(r0 + i) * Q))[tx] = o;
        }
    }
}

// ---------------------------------------------------------------------------
// Kernel 4: out[n] = temp[n] @ Zg[n], fp16 MFMA (counter-clean in r8).
// ---------------------------------------------------------------------------
__global__ __launch_bounds__(512) void apply_kernel(
    const float* __restrict__ X, const float* __restrict__ G,
    const float* __restrict__ lrp, const float* __restrict__ Zg,
    float* __restrict__ out)
{
    __shared__ __align__(16) unsigned char pool[65536];
    Half4* sTh = (Half4*)pool;
    Half4* sZh = (Half4*)(pool + 32768);

    const int n = blockIdx.x >> 3;
    const int p0 = (blockIdx.x & 7) * 128;
    const int tid = threadIdx.x;
    const float lr = *lrp;
    const float* xb = X + (size_t)n * P * Q + (size_t)p0 * Q;
    const float* gb = G + (size_t)n * P * Q + (size_t)p0 * Q;
    const float* zb = Zg + (size_t)n * Q * Q;
    float* ob = out + (size_t)n * P * Q + (size_t)p0 * Q;

#pragma unroll
    for (int t = 0; t < 8; ++t) {
        const int idx = tid + t * 512;
        const int row = idx >> 5, c4 = idx & 31;
        const float4 v = ((const float4*)zb)[idx];
        Half4 h;
        h.x = (_Float16)v.x; h.y = (_Float16)v.y;
        h.z = (_Float16)v.z; h.w = (_Float16)v.w;
        sZh[row * 32 + (c4 ^ (row & 15))] = h;
    }
#pragma unroll
    for (int t = 0; t < 8; ++t) {
        const int idx = tid + t * 512;
        const int row = idx >> 5, c4 = idx & 31;
        const float4 xv = ((const float4*)xb)[idx];
        const float4 gv = ((const float4*)gb)[idx];
        Half4 h;
        h.x = (_Float16)(xv.x - lr * gv.x);
        h.y = (_Float16)(xv.y - lr * gv.y);
        h.z = (_Float16)(xv.z - lr * gv.z);
        h.w = (_Float16)(xv.w - lr * gv.w);
        sTh[row * 32 + (c4 ^ (row & 15))] = h;
    }
    __syncthreads();

    const int lane = tid & 63;
    const int wid = tid >> 6;
    const int RB = wid * 16;
    const f32x4 zero4 = {0.0f, 0.0f, 0.0f, 0.0f};

    f32x4 a[8];
#pragma unroll
    for (int fj = 0; fj < 8; ++fj) a[fj] = zero4;
#pragma unroll
    for (int kb = 0; kb < 4; ++kb) {
        const half8 af = frag_ld(sTh, RB, kb * 8, lane);
#pragma unroll
        for (int fj = 0; fj < 8; ++fj) {
            const half8 bf = frag_ld(sZh, fj * 16, kb * 8, lane);
            a[fj] = __builtin_amdgcn_mfma_f32_16x16x32_f16(af, bf, a[fj], 0, 0, 0);
        }
    }

    const int m0 = (lane >> 4) * 4;
    const int nn = lane & 15;
#pragma unroll
    for (int fj = 0; fj < 8; ++fj) {
#pragma unroll
        for (int j = 0; j < 4; ++j) {
            ob[(size_t)(RB + m0 + j) * Q + fj * 16 + nn] = a[fj][j];
        }
    }
}

extern "C" void kernel_launch(void* const* d_in, const int* in_sizes, int n_in,
                              void* d_out, int out_size, void* d_ws, size_t ws_size,
                              hipStream_t stream) {
    const float* X  = (const float*)d_in[0];
    const float* G  = (const float*)d_in[1];
    const float* lr = (const float*)d_in[2];
    float* outp = (float*)d_out;

    const size_t QQ = (size_t)Q * Q;
    const size_t mat = (size_t)NBATCH * QQ;           // 16.8 MB (floats)

    // ws layout: [Zg][gram][parts 0..npart-1]; npart=1 aliases parts->gram.
    const int npart_want = 4;
    const size_t need4 = (2 + npart_want) * mat * sizeof(float);
    const int npart = (ws_size >= need4) ? npart_want : 1;

    float* Zg    = (float*)d_ws;
    float* gram  = Zg + mat;
    float* gpart = (npart == 1) ? gram : gram + mat;

    gram_kernel<<<NBATCH * npart, 256, 0, stream>>>(X, G, lr, gpart, npart);
    ns_kernel<<<NBATCH, 512, 0, stream>>>(gpart, npart, gram, Zg);
    refine_kernel<<<NBATCH, 512, 0, stream>>>(gram, Zg);
    apply_kernel<<<NBATCH * 8, 512, 0, stream>>>(X, G, lr, Zg, outp);
}

// Round 10
// 293.422 us; speedup vs baseline: 1.1916x; 1.1916x over previous
//
#include <hip/hip_runtime.h>

#define NBATCH 256
#define P 1024
#define Q 128
#define NS_LOOP 10

typedef _Float16 half8 __attribute__((ext_vector_type(8)));
typedef float f32x4 __attribute__((ext_vector_type(4)));
struct __attribute__((aligned(8))) Half4 { _Float16 x, y, z, w; };   // 8 bytes

// ---- swizzled fp16 machinery for ns/apply (unchanged, counter-clean) ----
__device__ __forceinline__ half8 frag_ld(const Half4* S, int rowbase, int slotbase, int lane) {
    const int r = rowbase + (lane & 15);
    const int g = (lane >> 4);
    const int rx = r & 15;
    const Half4 h1 = S[r * 32 + ((slotbase + g) ^ rx)];
    const Half4 h2 = S[r * 32 + ((slotbase + g + 4) ^ rx)];
    half8 v;
    v[0] = h1.x; v[1] = h1.y; v[2] = h1.z; v[3] = h1.w;
    v[4] = h2.x; v[5] = h2.y; v[6] = h2.z; v[7] = h2.w;
    return v;
}

__device__ __forceinline__ int cpos(int RB, int CB, int lane) {
    const int r = CB + (lane & 15);
    const int s = (RB >> 2) + (lane >> 4);
    return r * 32 + (s ^ (r & 15));
}

__device__ __forceinline__ f32x4 cread(const Half4* S, int p) {
    const Half4 h = S[p];
    f32x4 v;
    v[0] = (float)h.x; v[1] = (float)h.y; v[2] = (float)h.z; v[3] = (float)h.w;
    return v;
}

__device__ __forceinline__ void cwrite(Half4* S, int p, f32x4 v) {
    Half4 h;
    h.x = (_Float16)v[0]; h.y = (_Float16)v[1]; h.z = (_Float16)v[2]; h.w = (_Float16)v[3];
    S[p] = h;
}

// ---- pitch-36 transposed-chunk fragment read for gram MFMA ----
// LDS layout: [q=0..127][p=0..31], pitch 36 halves. Lane l reads row
// q = rowbase+(l&15), halves p = 4g..4g+3 and 16+4g..+3 (g = l>>4) —
// two contiguous b64s; bank walk 18·r covers all banks (optimal).
__device__ __forceinline__ half8 frag_ld36(const _Float16* S, int rowbase, int lane) {
    const int r = rowbase + (lane & 15);
    const int g = lane >> 4;
    const Half4 h1 = *(const Half4*)(S + r * 36 + 4 * g);
    const Half4 h2 = *(const Half4*)(S + r * 36 + 16 + 4 * g);
    half8 v;
    v[0] = h1.x; v[1] = h1.y; v[2] = h1.z; v[3] = h1.w;
    v[4] = h2.x; v[5] = h2.y; v[6] = h2.z; v[7] = h2.w;
    return v;
}

// ---------------------------------------------------------------------------
// Kernel 1: partial gram via fp16 MFMA with hi/lo split (fp32-grade).
// gram = hi^T hi + hi^T lo + lo^T hi  (lo^T lo ~ 2^-22 rel, dropped).
// Block (n,part): 256 p-rows, 8 chunks of 32. 512 thr = 8 waves, each owns
// a 16-row C strip. LDS 18.4KB -> 4 blocks/CU. Output symmetric -> layout-safe.
// ---------------------------------------------------------------------------
__global__ __launch_bounds__(512) void gram_kernel(
    const float* __restrict__ X, const float* __restrict__ G,
    const float* __restrict__ lrp, float* __restrict__ gpart, int npart)
{
    __shared__ _Float16 sHi[128 * 36];   // 9216 B
    __shared__ _Float16 sLo[128 * 36];   // 9216 B

    const int n = blockIdx.x / npart;
    const int part = blockIdx.x - n * npart;
    const int rows = P / npart;          // 256
    const float lr = *lrp;
    const float* xb = X + (size_t)n * P * Q;
    const float* gb = G + (size_t)n * P * Q;

    const int tid = threadIdx.x;
    const int lane = tid & 63;
    const int wid = tid >> 6;            // 8 waves
    const int RB = wid * 16;             // C-row strip

    const int q = tid & 127;             // staging: column owned
    const int ph = tid >> 7;             // 0..3

    const f32x4 zero4 = {0.0f, 0.0f, 0.0f, 0.0f};
    f32x4 acc[8];
#pragma unroll
    for (int fj = 0; fj < 8; ++fj) acc[fj] = zero4;

    for (int ch = 0; ch < rows / 32; ++ch) {
        const int pbase = part * rows + ch * 32;
        __syncthreads();   // previous chunk's reads done
        // stage transposed hi/lo: thread loads 4 consecutive-p scalars at
        // fixed q (wave-coalesced over q), writes contiguous Half4.
#pragma unroll
        for (int t = 0; t < 2; ++t) {
            const int p0 = ph * 4 + t * 16;      // chunk-local p
            Half4 hq, lq;
            _Float16* hp = (_Float16*)&hq;
            _Float16* lp = (_Float16*)&lq;
#pragma unroll
            for (int i = 0; i < 4; ++i) {
                const size_t off = (size_t)(pbase + p0 + i) * Q + q;
                const float v = xb[off] - lr * gb[off];
                const _Float16 hi = (_Float16)v;
                hp[i] = hi;
                lp[i] = (_Float16)(v - (float)hi);
            }
            *(Half4*)(sHi + q * 36 + p0) = hq;
            *(Half4*)(sLo + q * 36 + p0) = lq;
        }
        __syncthreads();

        const half8 ahi = frag_ld36(sHi, RB, lane);
        const half8 alo = frag_ld36(sLo, RB, lane);
#pragma unroll
        for (int fj = 0; fj < 8; ++fj) {
            const half8 bhi = frag_ld36(sHi, fj * 16, lane);
            const half8 blo = frag_ld36(sLo, fj * 16, lane);
            acc[fj] = __builtin_amdgcn_mfma_f32_16x16x32_f16(ahi, bhi, acc[fj], 0, 0, 0);
            acc[fj] = __builtin_amdgcn_mfma_f32_16x16x32_f16(ahi, blo, acc[fj], 0, 0, 0);
            acc[fj] = __builtin_amdgcn_mfma_f32_16x16x32_f16(alo, bhi, acc[fj], 0, 0, 0);
        }
    }

    // store partial gram (C layout as validated in r8's apply)
    float* gm = gpart + ((size_t)n * npart + part) * Q * Q;
    const int m0 = (lane >> 4) * 4;
    const int nn = lane & 15;
#pragma unroll
    for (int fj = 0; fj < 8; ++fj) {
#pragma unroll
        for (int j = 0; j < 4; ++j) {
            gm[(size_t)(RB + m0 + j) * Q + fj * 16 + nn] = acc[fj][j];
        }
    }
}

// ---------------------------------------------------------------------------
// Kernel 2: Newton-Schulz (fp16 MFMA). Sums npart partial grams at load,
// writes summed fp32 gram for the refiner. (r9, unchanged)
// ---------------------------------------------------------------------------
__global__ __launch_bounds__(512) void ns_kernel(
    const float* __restrict__ gpart, int npart,
    float* __restrict__ gram, float* __restrict__ Zg)
{
    __shared__ __align__(16) unsigned char pool[98304];
    Half4* bufA = (Half4*)pool;
    Half4* bufB = (Half4*)(pool + 32768);
    Half4* sZh  = (Half4*)(pool + 65536);
    __shared__ float sRed[8];

    const int n = blockIdx.x;
    const int tid = threadIdx.x;
    const float* gp = gpart + (size_t)n * npart * Q * Q;
    float* gmo = gram + (size_t)n * Q * Q;

    float4 gv[8];
    float ss = 0.0f;
#pragma unroll
    for (int t = 0; t < 8; ++t) {
        const int idx = tid + t * 512;
        float4 v = ((const float4*)gp)[idx];
        for (int pp = 1; pp < npart; ++pp) {
            const float4 w = ((const float4*)(gp + (size_t)pp * Q * Q))[idx];
            v.x += w.x; v.y += w.y; v.z += w.z; v.w += w.w;
        }
        gv[t] = v;
        ((float4*)gmo)[idx] = v;
        ss += v.x * v.x + v.y * v.y + v.z * v.z + v.w * v.w;
    }
#pragma unroll
    for (int off = 32; off > 0; off >>= 1) ss += __shfl_down(ss, off, 64);
    if ((tid & 63) == 0) sRed[tid >> 6] = ss;
    __syncthreads();
    float csum = 0.0f;
#pragma unroll
    for (int w = 0; w < 8; ++w) csum += sRed[w];
    const float c = sqrtf(csum);
    const float rc = 1.0f / c;
    const float rs = 1.0f / sqrtf(c);

#pragma unroll
    for (int t = 0; t < 8; ++t) {
        const int idx = tid + t * 512;
        const int row = idx >> 5, c4 = idx & 31;
        const int slot = row * 32 + (c4 ^ (row & 15));
        float wv[4], zv[4];
        wv[0] = gv[t].x * rc; wv[1] = gv[t].y * rc;
        wv[2] = gv[t].z * rc; wv[3] = gv[t].w * rc;
#pragma unroll
        for (int j = 0; j < 4; ++j)
            zv[j] = -0.5f * wv[j] + (((row >> 2) == c4 && (row & 3) == j) ? 1.5f : 0.0f);
        Half4 wh, zh;
        wh.x = (_Float16)wv[0]; wh.y = (_Float16)wv[1]; wh.z = (_Float16)wv[2]; wh.w = (_Float16)wv[3];
        zh.x = (_Float16)zv[0]; zh.y = (_Float16)zv[1]; zh.z = (_Float16)zv[2]; zh.w = (_Float16)zv[3];
        bufA[slot] = wh;
        sZh[slot] = zh;
    }
    __syncthreads();

    const int lane = tid & 63;
    const int wid = tid >> 6;
    const int RB = wid * 16;
    const f32x4 zero4 = {0.0f, 0.0f, 0.0f, 0.0f};
    Half4* cur = bufA;
    Half4* scr = bufB;

    for (int it = 0; it < NS_LOOP; ++it) {
        f32x4 a1[8];
#pragma unroll
        for (int fj = 0; fj < 8; ++fj) a1[fj] = zero4;
#pragma unroll
        for (int kb = 0; kb < 4; ++kb) {
            const half8 af = frag_ld(cur, RB, kb * 8, lane);
#pragma unroll
            for (int fj = 0; fj < 8; ++fj) {
                const half8 bf = frag_ld(cur, fj * 16, kb * 8, lane);
                a1[fj] = __builtin_amdgcn_mfma_f32_16x16x32_f16(af, bf, a1[fj], 0, 0, 0);
            }
        }
#pragma unroll
        for (int fj = 0; fj < 8; ++fj) {
            const int p = cpos(RB, fj * 16, lane);
            cwrite(scr, p, 1.5f * cread(cur, p) - 0.5f * a1[fj]);
        }
        __syncthreads();

        f32x4 a2[8];
#pragma unroll
        for (int fj = 0; fj < 8; ++fj) a2[fj] = zero4;
#pragma unroll
        for (int kb = 0; kb < 4; ++kb) {
            const half8 af = frag_ld(scr, RB, kb * 8, lane);
#pragma unroll
            for (int fj = 0; fj < 8; ++fj) {
                const half8 bf = frag_ld(cur, fj * 16, kb * 8, lane);
                a2[fj] = __builtin_amdgcn_mfma_f32_16x16x32_f16(af, bf, a2[fj], 0, 0, 0);
            }
        }
        f32x4 wn[8];
#pragma unroll
        for (int fj = 0; fj < 8; ++fj) {
            const int p = cpos(RB, fj * 16, lane);
            wn[fj] = 1.5f * cread(scr, p) - 0.5f * a2[fj];
        }
        __syncthreads();
#pragma unroll
        for (int fj = 0; fj < 8; ++fj)
            cwrite(scr, cpos(RB, fj * 16, lane), wn[fj]);
        __syncthreads();

        f32x4 a3[8];
#pragma unroll
        for (int fj = 0; fj < 8; ++fj) a3[fj] = zero4;
#pragma unroll
        for (int kb = 0; kb < 4; ++kb) {
            const half8 af = frag_ld(scr, RB, kb * 8, lane);
#pragma unroll
            for (int fj = 0; fj < 8; ++fj) {
                const half8 bf = frag_ld(sZh, fj * 16, kb * 8, lane);
                a3[fj] = __builtin_amdgcn_mfma_f32_16x16x32_f16(af, bf, a3[fj], 0, 0, 0);
            }
        }
        f32x4 zn[8];
#pragma unroll
        for (int fj = 0; fj < 8; ++fj) {
            const int p = cpos(RB, fj * 16, lane);
            zn[fj] = 1.5f * cread(sZh, p) - 0.5f * a3[fj];
        }
        __syncthreads();
#pragma unroll
        for (int fj = 0; fj < 8; ++fj)
            cwrite(sZh, cpos(RB, fj * 16, lane), zn[fj]);
        __syncthreads();

        Half4* tmp = cur; cur = scr; scr = tmp;
    }

    float* zo = Zg + (size_t)n * Q * Q;
#pragma unroll
    for (int t = 0; t < 8; ++t) {
        const int idx = tid + t * 512;
        const int row = idx >> 5, c4 = idx & 31;
        const Half4 h = sZh[row * 32 + (c4 ^ (row & 15))];
        float4 o;
        o.x = (float)h.x * rs; o.y = (float)h.y * rs;
        o.z = (float)h.z * rs; o.w = (float)h.w * rs;
        ((float4*)(zo + row * Q))[c4] = o;
    }
}

// ---------------------------------------------------------------------------
// Kernel 3: one fp32 NS refinement step (counter-clean, unchanged).
// ---------------------------------------------------------------------------
__global__ __launch_bounds__(512) void refine_kernel(
    const float* __restrict__ gram, float* __restrict__ Zg)
{
    __shared__ float sY[Q * Q];
    __shared__ float sU[Q * Q];
    __shared__ float sR[32 * Q];
    const int n = blockIdx.x;
    const int tid = threadIdx.x;
    const float* gm = gram + (size_t)n * Q * Q;
    float* zg = Zg + (size_t)n * Q * Q;
    const int ty = tid >> 5, tx = tid & 31;

#pragma unroll
    for (int t = 0; t < 8; ++t) {
        const int idx = tid + t * 512;
        ((float4*)sY)[idx] = ((const float4*)zg)[idx];
    }
    __syncthreads();

    {
        float acc[8][4];
#pragma unroll
        for (int i = 0; i < 8; ++i)
#pragma unroll
            for (int j = 0; j < 4; ++j) acc[i][j] = 0.0f;
        for (int k = 0; k < Q; ++k) {
            float a[8];
#pragma unroll
            for (int i = 0; i < 8; ++i) a[i] = sY[(ty * 8 + i) * Q + k];
            const float4 bv = ((const float4*)(sY + k * Q))[tx];
            const float b[4] = {bv.x, bv.y, bv.z, bv.w};
#pragma unroll
            for (int i = 0; i < 8; ++i)
#pragma unroll
                for (int j = 0; j < 4; ++j) acc[i][j] += a[i] * b[j];
        }
#pragma unroll
        for (int i = 0; i < 8; ++i) {
            float4 v = make_float4(acc[i][0], acc[i][1], acc[i][2], acc[i][3]);
            ((float4*)(sU + (ty * 8 + i) * Q))[tx] = v;
        }
    }
    __syncthreads();

    for (int ch = 0; ch < 4; ++ch) {
        const int r0 = ch * 32 + ty * 2;
        float acc[2][4];
#pragma unroll
        for (int i = 0; i < 2; ++i)
#pragma unroll
            for (int j = 0; j < 4; ++j) acc[i][j] = 0.0f;
        for (int k = 0; k < Q; ++k) {
            const float a0 = sY[(r0 + 0) * Q + k];
            const float a1 = sY[(r0 + 1) * Q + k];
            const float4 bv = ((const float4*)(gm + (size_t)k * Q))[tx];
            acc[0][0] += a0 * bv.x; acc[0][1] += a0 * bv.y;
            acc[0][2] += a0 * bv.z; acc[0][3] += a0 * bv.w;
            acc[1][0] += a1 * bv.x; acc[1][1] += a1 * bv.y;
            acc[1][2] += a1 * bv.z; acc[1][3] += a1 * bv.w;
        }
        __syncthreads();
#pragma unroll
        for (int i = 0; i < 2; ++i) {
            float4 v = make_float4(acc[i][0], acc[i][1], acc[i][2], acc[i][3]);
            ((float4*)(sR + (ty * 2 + i) * Q))[tx] = v;
        }
        __syncthreads();

        float acc2[2][4];
#pragma unroll
        for (int i = 0; i < 2; ++i)
#pragma unroll
            for (int j = 0; j < 4; ++j) acc2[i][j] = 0.0f;
        for (int k = 0; k < Q; ++k) {
            const float a0 = sR[(ty * 2 + 0) * Q + k];
            const float a1 = sR[(ty * 2 + 1) * Q + k];
            const float4 bv = ((const float4*)(sU + k * Q))[tx];
            acc2[0][0] += a0 * bv.x; acc2[0][1] += a0 * bv.y;
            acc2[0][2] += a0 * bv.z; acc2[0][3] += a0 * bv.w;
            acc2[1][0] += a1 * bv.x; acc2[1][1] += a1 * bv.y;
            acc2[1][2] += a1 * bv.z; acc2[1][3] += a1 * bv.w;
        }
#pragma unroll
        for (int i = 0; i < 2; ++i) {
            const float4 yv = ((const float4*)(sY + (r0 + i) * Q))[tx];
            float4 o;
            o.x = 1.5f * yv.x - 0.5f * acc2[i][0];
            o.y = 1.5f * yv.y - 0.5f * acc2[i][1];
            o.z = 1.5f * yv.z - 0.5f * acc2[i][2];
            o.w = 1.5f * yv.w - 0.5f * acc2[i][3];
            ((float4*)(zg + (size_t)(r0 + i) * Q))[tx] = o;
        }
    }
}

// ---------------------------------------------------------------------------
// Kernel 4: out[n] = temp[n] @ Zg[n], fp16 MFMA (counter-clean, unchanged).
// ---------------------------------------------------------------------------
__global__ __launch_bounds__(512) void apply_kernel(
    const float* __restrict__ X, const float* __restrict__ G,
    const float* __restrict__ lrp, const float* __restrict__ Zg,
    float* __restrict__ out)
{
    __shared__ __align__(16) unsigned char pool[65536];
    Half4* sTh = (Half4*)pool;
    Half4* sZh = (Half4*)(pool + 32768);

    const int n = blockIdx.x >> 3;
    const int p0 = (blockIdx.x & 7) * 128;
    const int tid = threadIdx.x;
    const float lr = *lrp;
    const float* xb = X + (size_t)n * P * Q + (size_t)p0 * Q;
    const float* gb = G + (size_t)n * P * Q + (size_t)p0 * Q;
    const float* zb = Zg + (size_t)n * Q * Q;
    float* ob = out + (size_t)n * P * Q + (size_t)p0 * Q;

#pragma unroll
    for (int t = 0; t < 8; ++t) {
        const int idx = tid + t * 512;
        const int row = idx >> 5, c4 = idx & 31;
        const float4 v = ((const float4*)zb)[idx];
        Half4 h;
        h.x = (_Float16)v.x; h.y = (_Float16)v.y;
        h.z = (_Float16)v.z; h.w = (_Float16)v.w;
        sZh[row * 32 + (c4 ^ (row & 15))] = h;
    }
#pragma unroll
    for (int t = 0; t < 8; ++t) {
        const int idx = tid + t * 512;
        const int row = idx >> 5, c4 = idx & 31;
        const float4 xv = ((const float4*)xb)[idx];
        const float4 gv = ((const float4*)gb)[idx];
        Half4 h;
        h.x = (_Float16)(xv.x - lr * gv.x);
        h.y = (_Float16)(xv.y - lr * gv.y);
        h.z = (_Float16)(xv.z - lr * gv.z);
        h.w = (_Float16)(xv.w - lr * gv.w);
        sTh[row * 32 + (c4 ^ (row & 15))] = h;
    }
    __syncthreads();

    const int lane = tid & 63;
    const int wid = tid >> 6;
    const int RB = wid * 16;
    const f32x4 zero4 = {0.0f, 0.0f, 0.0f, 0.0f};

    f32x4 a[8];
#pragma unroll
    for (int fj = 0; fj < 8; ++fj) a[fj] = zero4;
#pragma unroll
    for (int kb = 0; kb < 4; ++kb) {
        const half8 af = frag_ld(sTh, RB, kb * 8, lane);
#pragma unroll
        for (int fj = 0; fj < 8; ++fj) {
            const half8 bf = frag_ld(sZh, fj * 16, kb * 8, lane);
            a[fj] = __builtin_amdgcn_mfma_f32_16x16x32_f16(af, bf, a[fj], 0, 0, 0);
        }
    }

    const int m0 = (lane >> 4) * 4;
    const int nn = lane & 15;
#pragma unroll
    for (int fj = 0; fj < 8; ++fj) {
#pragma unroll
        for (int j = 0; j < 4; ++j) {
            ob[(size_t)(RB + m0 + j) * Q + fj * 16 + nn] = a[fj][j];
        }
    }
}

extern "C" void kernel_launch(void* const* d_in, const int* in_sizes, int n_in,
                              void* d_out, int out_size, void* d_ws, size_t ws_size,
                              hipStream_t stream) {
    const float* X  = (const float*)d_in[0];
    const float* G  = (const float*)d_in[1];
    const float* lr = (const float*)d_in[2];
    float* outp = (float*)d_out;

    const size_t QQ = (size_t)Q * Q;
    const size_t mat = (size_t)NBATCH * QQ;

    const int npart_want = 4;
    const size_t need4 = (2 + npart_want) * mat * sizeof(float);
    const int npart = (ws_size >= need4) ? npart_want : 1;

    float* Zg    = (float*)d_ws;
    float* gram  = Zg + mat;
    float* gpart = (npart == 1) ? gram : gram + mat;

    gram_kernel<<<NBATCH * npart, 512, 0, stream>>>(X, G, lr, gpart, npart);
    ns_kernel<<<NBATCH, 512, 0, stream>>>(gpart, npart, gram, Zg);
    refine_kernel<<<NBATCH, 512, 0, stream>>>(gram, Zg);
    apply_kernel<<<NBATCH * 8, 512, 0, stream>>>(X, G, lr, Zg, outp);
}

// Round 11
// 228.840 us; speedup vs baseline: 1.5279x; 1.2822x over previous
//
#include <hip/hip_runtime.h>

#define NBATCH 256
#define P 1024
#define Q 128
#define NS_LOOP 8   // + init T0 = 9 applications; exact-math residual <1e-4,
                    // below the fp16 noise floor the fused refine removes.

typedef _Float16 half8 __attribute__((ext_vector_type(8)));
typedef float f32x4 __attribute__((ext_vector_type(4)));
struct __attribute__((aligned(8))) Half4 { _Float16 x, y, z, w; };   // 8 bytes

// ---- swizzled fp16 machinery (counter-clean since r6) ----
// element (r,c) -> Half4 slot r*32 + ((c>>2) ^ (r&15)), component c&3.
// Convention: mfma(frag_ld(A,RB), frag_ld(B,CB)) = A_rows · B_rows^T block;
// cpos/cwrite stores the accumulator TRANSPOSED.
__device__ __forceinline__ half8 frag_ld(const Half4* S, int rowbase, int slotbase, int lane) {
    const int r = rowbase + (lane & 15);
    const int g = (lane >> 4);
    const int rx = r & 15;
    const Half4 h1 = S[r * 32 + ((slotbase + g) ^ rx)];
    const Half4 h2 = S[r * 32 + ((slotbase + g + 4) ^ rx)];
    half8 v;
    v[0] = h1.x; v[1] = h1.y; v[2] = h1.z; v[3] = h1.w;
    v[4] = h2.x; v[5] = h2.y; v[6] = h2.z; v[7] = h2.w;
    return v;
}

__device__ __forceinline__ int cpos(int RB, int CB, int lane) {
    const int r = CB + (lane & 15);
    const int s = (RB >> 2) + (lane >> 4);
    return r * 32 + (s ^ (r & 15));
}

__device__ __forceinline__ f32x4 cread(const Half4* S, int p) {
    const Half4 h = S[p];
    f32x4 v;
    v[0] = (float)h.x; v[1] = (float)h.y; v[2] = (float)h.z; v[3] = (float)h.w;
    return v;
}

__device__ __forceinline__ void cwrite(Half4* S, int p, f32x4 v) {
    Half4 h;
    h.x = (_Float16)v[0]; h.y = (_Float16)v[1]; h.z = (_Float16)v[2]; h.w = (_Float16)v[3];
    S[p] = h;
}

// split fp32 accumulator into hi/lo fp16 pair
__device__ __forceinline__ void cwrite_hl(Half4* Sh, Half4* Sl, int p, f32x4 v) {
    Half4 h, l;
    h.x = (_Float16)v[0]; h.y = (_Float16)v[1]; h.z = (_Float16)v[2]; h.w = (_Float16)v[3];
    l.x = (_Float16)(v[0] - (float)h.x);
    l.y = (_Float16)(v[1] - (float)h.y);
    l.z = (_Float16)(v[2] - (float)h.z);
    l.w = (_Float16)(v[3] - (float)h.w);
    Sh[p] = h; Sl[p] = l;
}

// ---- pitch-36 transposed-chunk fragment read for gram MFMA ----
__device__ __forceinline__ half8 frag_ld36(const _Float16* S, int rowbase, int lane) {
    const int r = rowbase + (lane & 15);
    const int g = lane >> 4;
    const Half4 h1 = *(const Half4*)(S + r * 36 + 4 * g);
    const Half4 h2 = *(const Half4*)(S + r * 36 + 16 + 4 * g);
    half8 v;
    v[0] = h1.x; v[1] = h1.y; v[2] = h1.z; v[3] = h1.w;
    v[4] = h2.x; v[5] = h2.y; v[6] = h2.z; v[7] = h2.w;
    return v;
}

// ---------------------------------------------------------------------------
// Kernel 1: partial gram via fp16 MFMA hi/lo split (r10, counter-clean).
// ---------------------------------------------------------------------------
__global__ __launch_bounds__(512) void gram_kernel(
    const float* __restrict__ X, const float* __restrict__ G,
    const float* __restrict__ lrp, float* __restrict__ gpart, int npart)
{
    __shared__ _Float16 sHi[128 * 36];
    __shared__ _Float16 sLo[128 * 36];

    const int n = blockIdx.x / npart;
    const int part = blockIdx.x - n * npart;
    const int rows = P / npart;
    const float lr = *lrp;
    const float* xb = X + (size_t)n * P * Q;
    const float* gb = G + (size_t)n * P * Q;

    const int tid = threadIdx.x;
    const int lane = tid & 63;
    const int wid = tid >> 6;
    const int RB = wid * 16;

    const int q = tid & 127;
    const int ph = tid >> 7;

    const f32x4 zero4 = {0.0f, 0.0f, 0.0f, 0.0f};
    f32x4 acc[8];
#pragma unroll
    for (int fj = 0; fj < 8; ++fj) acc[fj] = zero4;

    for (int ch = 0; ch < rows / 32; ++ch) {
        const int pbase = part * rows + ch * 32;
        __syncthreads();
#pragma unroll
        for (int t = 0; t < 2; ++t) {
            const int p0 = ph * 4 + t * 16;
            Half4 hq, lq;
            _Float16* hp = (_Float16*)&hq;
            _Float16* lp = (_Float16*)&lq;
#pragma unroll
            for (int i = 0; i < 4; ++i) {
                const size_t off = (size_t)(pbase + p0 + i) * Q + q;
                const float v = xb[off] - lr * gb[off];
                const _Float16 hi = (_Float16)v;
                hp[i] = hi;
                lp[i] = (_Float16)(v - (float)hi);
            }
            *(Half4*)(sHi + q * 36 + p0) = hq;
            *(Half4*)(sLo + q * 36 + p0) = lq;
        }
        __syncthreads();

        const half8 ahi = frag_ld36(sHi, RB, lane);
        const half8 alo = frag_ld36(sLo, RB, lane);
#pragma unroll
        for (int fj = 0; fj < 8; ++fj) {
            const half8 bhi = frag_ld36(sHi, fj * 16, lane);
            const half8 blo = frag_ld36(sLo, fj * 16, lane);
            acc[fj] = __builtin_amdgcn_mfma_f32_16x16x32_f16(ahi, bhi, acc[fj], 0, 0, 0);
            acc[fj] = __builtin_amdgcn_mfma_f32_16x16x32_f16(ahi, blo, acc[fj], 0, 0, 0);
            acc[fj] = __builtin_amdgcn_mfma_f32_16x16x32_f16(alo, bhi, acc[fj], 0, 0, 0);
        }
    }

    float* gm = gpart + ((size_t)n * npart + part) * Q * Q;
    const int m0 = (lane >> 4) * 4;
    const int nn = lane & 15;
#pragma unroll
    for (int fj = 0; fj < 8; ++fj) {
#pragma unroll
        for (int j = 0; j < 4; ++j) {
            gm[(size_t)(RB + m0 + j) * Q + fj * 16 + nn] = acc[fj][j];
        }
    }
}

// ---------------------------------------------------------------------------
// Kernel 2: Newton-Schulz (fp16 MFMA) + FUSED fp32-grade refinement.
// LDS 160KB: bufA/bufB (W ping-pong, then r-hi/lo), sZh (Z), bufC/bufD
// (A hi/lo staged at init, then u hi/lo). sRed aliases bufA (consumed
// before any staging write; extra barrier guards the alias).
// Refine (exact operand order, z symmetrized exactly first):
//   u = z*z (exact, symmetric); ř = A*z (cpos-stored => rows of z*A);
//   d = (z*A)*u;  Z_ref = rs*(1.5 z - 0.5 d)   [rs^2*c = 1 folds scales]
// ---------------------------------------------------------------------------
__global__ __launch_bounds__(512) void ns_kernel(
    const float* __restrict__ gpart, int npart, float* __restrict__ Zg)
{
    __shared__ __align__(16) unsigned char pool[163840];
    Half4* bufA = (Half4*)pool;               // W ping / r-hi
    Half4* bufB = (Half4*)(pool + 32768);     // W pong / r-lo
    Half4* sZh  = (Half4*)(pool + 65536);     // Z iterate
    Half4* bufC = (Half4*)(pool + 98304);     // A-hi / u-hi
    Half4* bufD = (Half4*)(pool + 131072);    // A-lo / u-lo
    float* sRed = (float*)pool;               // aliases bufA head (guarded)

    const int n = blockIdx.x;
    const int tid = threadIdx.x;
    const float* gp = gpart + (size_t)n * npart * Q * Q;

    // ---- load + sum partial grams, Frobenius norm ----
    float4 gv[8];
    float ss = 0.0f;
#pragma unroll
    for (int t = 0; t < 8; ++t) {
        const int idx = tid + t * 512;
        float4 v = ((const float4*)gp)[idx];
        for (int pp = 1; pp < npart; ++pp) {
            const float4 w = ((const float4*)(gp + (size_t)pp * Q * Q))[idx];
            v.x += w.x; v.y += w.y; v.z += w.z; v.w += w.w;
        }
        gv[t] = v;
        ss += v.x * v.x + v.y * v.y + v.z * v.z + v.w * v.w;
    }
#pragma unroll
    for (int off = 32; off > 0; off >>= 1) ss += __shfl_down(ss, off, 64);
    if ((tid & 63) == 0) sRed[tid >> 6] = ss;
    __syncthreads();
    float csum = 0.0f;
#pragma unroll
    for (int w = 0; w < 8; ++w) csum += sRed[w];
    __syncthreads();   // sRed reads done before bufA staging overwrites alias
    const float c = sqrtf(csum);
    const float rc = 1.0f / c;
    const float rs = 1.0f / sqrtf(c);

    // ---- init: A = gram*rc hi/lo -> bufC/bufD; W0 = A-hi -> bufA;
    //            Z0 = 1.5I - 0.5*A -> sZh ----
#pragma unroll
    for (int t = 0; t < 8; ++t) {
        const int idx = tid + t * 512;
        const int row = idx >> 5, c4 = idx & 31;
        const int slot = row * 32 + (c4 ^ (row & 15));
        float wv[4], zv[4];
        wv[0] = gv[t].x * rc; wv[1] = gv[t].y * rc;
        wv[2] = gv[t].z * rc; wv[3] = gv[t].w * rc;
        Half4 wh, wl, zh;
        _Float16* whp = (_Float16*)&wh;
        _Float16* wlp = (_Float16*)&wl;
        _Float16* zhp = (_Float16*)&zh;
#pragma unroll
        for (int j = 0; j < 4; ++j) {
            const _Float16 h = (_Float16)wv[j];
            whp[j] = h;
            wlp[j] = (_Float16)(wv[j] - (float)h);
            zv[j] = -0.5f * wv[j] + (((row >> 2) == c4 && (row & 3) == j) ? 1.5f : 0.0f);
            zhp[j] = (_Float16)zv[j];
        }
        bufA[slot] = wh;   // W0
        bufC[slot] = wh;   // A-hi (survives NS loop)
        bufD[slot] = wl;   // A-lo
        sZh[slot] = zh;
    }
    __syncthreads();

    const int lane = tid & 63;
    const int wid = tid >> 6;
    const int RB = wid * 16;
    const f32x4 zero4 = {0.0f, 0.0f, 0.0f, 0.0f};
    Half4* cur = bufA;
    Half4* scr = bufB;

    // ================= NS loop (fp16) =================
    for (int it = 0; it < NS_LOOP; ++it) {
        f32x4 a1[8];
#pragma unroll
        for (int fj = 0; fj < 8; ++fj) a1[fj] = zero4;
#pragma unroll
        for (int kb = 0; kb < 4; ++kb) {
            const half8 af = frag_ld(cur, RB, kb * 8, lane);
#pragma unroll
            for (int fj = 0; fj < 8; ++fj) {
                const half8 bf = frag_ld(cur, fj * 16, kb * 8, lane);
                a1[fj] = __builtin_amdgcn_mfma_f32_16x16x32_f16(af, bf, a1[fj], 0, 0, 0);
            }
        }
#pragma unroll
        for (int fj = 0; fj < 8; ++fj) {
            const int p = cpos(RB, fj * 16, lane);
            cwrite(scr, p, 1.5f * cread(cur, p) - 0.5f * a1[fj]);
        }
        __syncthreads();

        f32x4 a2[8];
#pragma unroll
        for (int fj = 0; fj < 8; ++fj) a2[fj] = zero4;
#pragma unroll
        for (int kb = 0; kb < 4; ++kb) {
            const half8 af = frag_ld(scr, RB, kb * 8, lane);
#pragma unroll
            for (int fj = 0; fj < 8; ++fj) {
                const half8 bf = frag_ld(cur, fj * 16, kb * 8, lane);
                a2[fj] = __builtin_amdgcn_mfma_f32_16x16x32_f16(af, bf, a2[fj], 0, 0, 0);
            }
        }
        f32x4 wn[8];
#pragma unroll
        for (int fj = 0; fj < 8; ++fj) {
            const int p = cpos(RB, fj * 16, lane);
            wn[fj] = 1.5f * cread(scr, p) - 0.5f * a2[fj];
        }
        __syncthreads();
#pragma unroll
        for (int fj = 0; fj < 8; ++fj)
            cwrite(scr, cpos(RB, fj * 16, lane), wn[fj]);
        __syncthreads();

        f32x4 a3[8];
#pragma unroll
        for (int fj = 0; fj < 8; ++fj) a3[fj] = zero4;
#pragma unroll
        for (int kb = 0; kb < 4; ++kb) {
            const half8 af = frag_ld(scr, RB, kb * 8, lane);
#pragma unroll
            for (int fj = 0; fj < 8; ++fj) {
                const half8 bf = frag_ld(sZh, fj * 16, kb * 8, lane);
                a3[fj] = __builtin_amdgcn_mfma_f32_16x16x32_f16(af, bf, a3[fj], 0, 0, 0);
            }
        }
        f32x4 zn[8];
#pragma unroll
        for (int fj = 0; fj < 8; ++fj) {
            const int p = cpos(RB, fj * 16, lane);
            zn[fj] = 1.5f * cread(sZh, p) - 0.5f * a3[fj];
        }
        __syncthreads();
#pragma unroll
        for (int fj = 0; fj < 8; ++fj)
            cwrite(sZh, cpos(RB, fj * 16, lane), zn[fj]);
        __syncthreads();

        Half4* tmp = cur; cur = scr; scr = tmp;
    }

    // ================= fused refinement =================
    // 0) symmetrize z exactly (makes z*z^T == z*z and cread(z^T) == z exact)
    {
        _Float16* zp = (_Float16*)sZh;
        for (int k = tid; k < Q * Q; k += 512) {
            const int r = k >> 7, cc = k & 127;
            if (r < cc) {
                const int i1 = (r * 32 + ((cc >> 2) ^ (r & 15))) * 4 + (cc & 3);
                const int i2 = (cc * 32 + ((r >> 2) ^ (cc & 15))) * 4 + (r & 3);
                const _Float16 av = (_Float16)(0.5f * ((float)zp[i1] + (float)zp[i2]));
                zp[i1] = av; zp[i2] = av;
            }
        }
    }
    __syncthreads();

    // a) racc = A*z (A hi/lo from bufC/D) -> cpos store = rows of (z*A)
    f32x4 racc[8];
#pragma unroll
    for (int fj = 0; fj < 8; ++fj) racc[fj] = zero4;
#pragma unroll
    for (int kb = 0; kb < 4; ++kb) {
        const half8 ah = frag_ld(bufC, RB, kb * 8, lane);
        const half8 al = frag_ld(bufD, RB, kb * 8, lane);
#pragma unroll
        for (int fj = 0; fj < 8; ++fj) {
            const half8 bz = frag_ld(sZh, fj * 16, kb * 8, lane);
            racc[fj] = __builtin_amdgcn_mfma_f32_16x16x32_f16(ah, bz, racc[fj], 0, 0, 0);
            racc[fj] = __builtin_amdgcn_mfma_f32_16x16x32_f16(al, bz, racc[fj], 0, 0, 0);
        }
    }
#pragma unroll
    for (int fj = 0; fj < 8; ++fj)
        cwrite_hl(bufA, bufB, cpos(RB, fj * 16, lane), racc[fj]);
    __syncthreads();   // A reads done (bufC/D now overwritable); r visible

    // b) uacc = z*z (exact symmetric) -> bufC/bufD hi/lo
    f32x4 uacc[8];
#pragma unroll
    for (int fj = 0; fj < 8; ++fj) uacc[fj] = zero4;
#pragma unroll
    for (int kb = 0; kb < 4; ++kb) {
        const half8 az = frag_ld(sZh, RB, kb * 8, lane);
#pragma unroll
        for (int fj = 0; fj < 8; ++fj) {
            const half8 bz = frag_ld(sZh, fj * 16, kb * 8, lane);
            uacc[fj] = __builtin_amdgcn_mfma_f32_16x16x32_f16(az, bz, uacc[fj], 0, 0, 0);
        }
    }
#pragma unroll
    for (int fj = 0; fj < 8; ++fj)
        cwrite_hl(bufC, bufD, cpos(RB, fj * 16, lane), uacc[fj]);
    __syncthreads();   // u visible

    // c) d = (z*A)*u, 3 hi/lo chains; Z_ref = rs*(1.5 z - 0.5 d) -> Zg
    f32x4 dacc[8];
#pragma unroll
    for (int fj = 0; fj < 8; ++fj) dacc[fj] = zero4;
#pragma unroll
    for (int kb = 0; kb < 4; ++kb) {
        const half8 rh = frag_ld(bufA, RB, kb * 8, lane);
        const half8 rl = frag_ld(bufB, RB, kb * 8, lane);
#pragma unroll
        for (int fj = 0; fj < 8; ++fj) {
            const half8 uh = frag_ld(bufC, fj * 16, kb * 8, lane);
            const half8 ul = frag_ld(bufD, fj * 16, kb * 8, lane);
            dacc[fj] = __builtin_amdgcn_mfma_f32_16x16x32_f16(rh, uh, dacc[fj], 0, 0, 0);
            dacc[fj] = __builtin_amdgcn_mfma_f32_16x16x32_f16(rh, ul, dacc[fj], 0, 0, 0);
            dacc[fj] = __builtin_amdgcn_mfma_f32_16x16x32_f16(rl, uh, dacc[fj], 0, 0, 0);
        }
    }

    float* zo = Zg + (size_t)n * Q * Q;
    const int m0 = (lane >> 4) * 4;
    const int nn = lane & 15;
#pragma unroll
    for (int fj = 0; fj < 8; ++fj) {
        const f32x4 zq = cread(sZh, cpos(RB, fj * 16, lane));
#pragma unroll
        for (int j = 0; j < 4; ++j) {
            zo[(size_t)(RB + m0 + j) * Q + fj * 16 + nn] =
                rs * (1.5f * zq[j] - 0.5f * dacc[fj][j]);
        }
    }
}

// ---------------------------------------------------------------------------
// Kernel 3: out[n] = temp[n] @ Zg[n], fp16 MFMA (r8, counter-clean).
// ---------------------------------------------------------------------------
__global__ __launch_bounds__(512) void apply_kernel(
    const float* __restrict__ X, const float* __restrict__ G,
    const float* __restrict__ lrp, const float* __restrict__ Zg,
    float* __restrict__ out)
{
    __shared__ __align__(16) unsigned char pool[65536];
    Half4* sTh = (Half4*)pool;
    Half4* sZh = (Half4*)(pool + 32768);

    const int n = blockIdx.x >> 3;
    const int p0 = (blockIdx.x & 7) * 128;
    const int tid = threadIdx.x;
    const float lr = *lrp;
    const float* xb = X + (size_t)n * P * Q + (size_t)p0 * Q;
    const float* gb = G + (size_t)n * P * Q + (size_t)p0 * Q;
    const float* zb = Zg + (size_t)n * Q * Q;
    float* ob = out + (size_t)n * P * Q + (size_t)p0 * Q;

#pragma unroll
    for (int t = 0; t < 8; ++t) {
        const int idx = tid + t * 512;
        const int row = idx >> 5, c4 = idx & 31;
        const float4 v = ((const float4*)zb)[idx];
        Half4 h;
        h.x = (_Float16)v.x; h.y = (_Float16)v.y;
        h.z = (_Float16)v.z; h.w = (_Float16)v.w;
        sZh[row * 32 + (c4 ^ (row & 15))] = h;
    }
#pragma unroll
    for (int t = 0; t < 8; ++t) {
        const int idx = tid + t * 512;
        const int row = idx >> 5, c4 = idx & 31;
        const float4 xv = ((const float4*)xb)[idx];
        const float4 gv = ((const float4*)gb)[idx];
        Half4 h;
        h.x = (_Float16)(xv.x - lr * gv.x);
        h.y = (_Float16)(xv.y - lr * gv.y);
        h.z = (_Float16)(xv.z - lr * gv.z);
        h.w = (_Float16)(xv.w - lr * gv.w);
        sTh[row * 32 + (c4 ^ (row & 15))] = h;
    }
    __syncthreads();

    const int lane = tid & 63;
    const int wid = tid >> 6;
    const int RB = wid * 16;
    const f32x4 zero4 = {0.0f, 0.0f, 0.0f, 0.0f};

    f32x4 a[8];
#pragma unroll
    for (int fj = 0; fj < 8; ++fj) a[fj] = zero4;
#pragma unroll
    for (int kb = 0; kb < 4; ++kb) {
        const half8 af = frag_ld(sTh, RB, kb * 8, lane);
#pragma unroll
        for (int fj = 0; fj < 8; ++fj) {
            const half8 bf = frag_ld(sZh, fj * 16, kb * 8, lane);
            a[fj] = __builtin_amdgcn_mfma_f32_16x16x32_f16(af, bf, a[fj], 0, 0, 0);
        }
    }

    const int m0 = (lane >> 4) * 4;
    const int nn = lane & 15;
#pragma unroll
    for (int fj = 0; fj < 8; ++fj) {
#pragma unroll
        for (int j = 0; j < 4; ++j) {
            ob[(size_t)(RB + m0 + j) * Q + fj * 16 + nn] = a[fj][j];
        }
    }
}

extern "C" void kernel_launch(void* const* d_in, const int* in_sizes, int n_in,
                              void* d_out, int out_size, void* d_ws, size_t ws_size,
                              hipStream_t stream) {
    const float* X  = (const float*)d_in[0];
    const float* G  = (const float*)d_in[1];
    const float* lr = (const float*)d_in[2];
    float* outp = (float*)d_out;

    const size_t QQ = (size_t)Q * Q;
    const size_t mat = (size_t)NBATCH * QQ;

    const int npart_want = 4;
    const size_t need = (1 + npart_want) * mat * sizeof(float);
    const int npart = (ws_size >= need) ? npart_want : 1;

    float* Zg    = (float*)d_ws;
    float* gpart = Zg + mat;

    gram_kernel<<<NBATCH * npart, 512, 0, stream>>>(X, G, lr, gpart, npart);
    ns_kernel<<<NBATCH, 512, 0, stream>>>(gpart, npart, Zg);
    apply_kernel<<<NBATCH * 8, 512, 0, stream>>>(X, G, lr, Zg, outp);
}